// Round 8
// baseline (1610.737 us; speedup 1.0000x reference)
//
#include <hip/hip_runtime.h>

typedef unsigned long long u64;
typedef unsigned int u32;
typedef float f2 __attribute__((ext_vector_type(2)));

#define TSTEPS 8192
#define NSEG   2048
#define DTC    0.025f

// Persistent packed-pair halo decomposition at FULL-CHIP geometry:
// 256 blocks x 64 lanes, 2 adjacent segs/lane (packed fp32 v_pk_* VALU).
// Wave spans 128 segs; owned segs [8b, 8b+8) live in lanes 30..33, valid for
// K=60 steps (cone: 2j-K>=0 && 2j+1+K<=127 -> j in [30,33]). 137 phases
// (136x60 + 32 tail) instead of 293. Fence-free inter-block sync via
// (tag<<32|f32bits) relaxed agent-scope atomics (value rides with the tag --
// no fences, no L2 invalidation). Owned lanes keep state in registers across
// phases; outputs buffered in LDS, bulk-dumped coalesced at phase end.
#define KST    60
#define KTAIL  32
#define WAVE   64
#define COWN   8
#define NBLK   (NSEG / COWN)                 // 256
#define NPH    137                           // 136*60 + 32 = 8192
#define JLO    30                            // owned lanes [30, 34)
#define PF     8                             // rolling stim prefetch depth
#define LROW   18                            // LDS row stride in floats (8B-aligned rows)

constexpr double L2E = 1.4426950408889634074;   // log2(e)

#define AM_A ((float)(-0.1 * L2E))              // em0 = exp2(AM_A*V) = e^{-0.1V}
#define CEM  0.018315638888734179f              // e^-4    -> am's exp
#define CEH  0.030197383422318501f              // e^-3.5  -> bh's exp
#define CEN  0.0040867714384640666f             // e^-5.5  -> an's exp
#define BM_A ((float)(-L2E / 18.0))
#define BM_B ((float)(2.0 - 65.0 * L2E / 18.0)) // bm = 4e^{-(V+65)/18}
#define QA   ((float)(-L2E / 80.0))
#define QB   ((float)(-65.0 * L2E / 80.0))      // q = e^{-(V+65)/80}; bn=q/8; ah=0.07q^4
#define CAH  0.2645751311064591f                // sqrt(0.07)

#define AL(p) __hip_atomic_load((p), __ATOMIC_RELAXED, __HIP_MEMORY_SCOPE_AGENT)
#define AS(p, v) __hip_atomic_store((p), (v), __ATOMIC_RELAXED, __HIP_MEMORY_SCOPE_AGENT)

__device__ __forceinline__ f2 exp2v(f2 x) {
    f2 r; r.x = __builtin_amdgcn_exp2f(x.x); r.y = __builtin_amdgcn_exp2f(x.y);
    return r;
}
__device__ __forceinline__ f2 rcpv(f2 x) {
    f2 r; r.x = __builtin_amdgcn_rcpf(x.x); r.y = __builtin_amdgcn_rcpf(x.y);
    return r;
}
__device__ __forceinline__ u64 pack_tag(float v, int tag) {
    return ((u64)(u32)tag << 32) | (u64)__float_as_uint(v);
}
__device__ __forceinline__ float lo_f(u64 w) { return __uint_as_float((u32)w); }

__device__ __forceinline__ void hh_step2(
    f2& V, f2& m, f2& h, f2& n, f2 is,
    bool le, bool re, f2 gna, f2 gk, f2 gl, f2 gax,
    f2& mc, f2& vp)
{
    // shuffles first: ds latency overlaps the rate math; in-pair neighbors
    // are register-local
    const float vl0 = __shfl_up(V.y, 1);
    const float vr1 = __shfl_down(V.x, 1);
    f2 Vl, Vr;
    Vl.x = le ? V.x : vl0;   Vl.y = V.x;
    Vr.x = V.y;              Vr.y = re ? V.y : vr1;

    // rates: 3 exp2 + 1 rcp per segment (shared e^{-0.1V}; 3 reciprocals
    // recovered from one rcp of the denominator product)
    const f2 em0 = exp2v(V * AM_A);
    const f2 da  = 1.0f - CEM * em0;          // am denom
    const f2 db  = 1.0f - CEN * em0;          // an denom
    const f2 dc  = 1.0f + CEH * em0;          // bh denom
    const f2 dab = da * db;
    const f2 r3  = rcpv(dab * dc);
    const f2 rab = dc * r3;                   // 1/(da*db)
    const f2 am  = (0.1f * V + 4.0f)   * (db * rab);
    const f2 an  = (0.01f * V + 0.55f) * (da * rab);
    const f2 bh  = dab * r3;                  // 1/dc
    const f2 bm  = exp2v(V * BM_A + BM_B);
    const f2 q   = exp2v(V * QA + QB);
    const f2 tq  = CAH * (q * q);
    const f2 ah  = tq * tq;                   // 0.07 * q^4
    const f2 bn  = 0.125f * q;

    const f2 m3 = m * m * m;
    const f2 n2 = n * n;
    const f2 i_ion = gna * m3 * h * (V - 50.0f)
                   + gk * (n2 * n2) * (V + 77.0f)
                   + gl * (V + 54.387f);
    const f2 ax = (Vl + Vr) - 2.0f * V;
    const f2 dV = gax * ax + (is - i_ion);    // CM = 1

    mc = dV + i_ion;                          // mem_cur
    vp = V;                                   // pre-update V

    V = V + DTC * dV;
    m = m + DTC * (am - (am + bm) * m);
    h = h + DTC * (ah - (ah + bh) * h);
    n = n + DTC * (an - (an + bn) * n);
}

template <int KS>
__device__ __forceinline__ void run_phase(
    int p, int b, int j, int s0, int sc0,
    bool owned, bool le, bool re,
    f2 gna, f2 gk, f2 gl, f2 gax,
    const float* __restrict__ stim, u64* __restrict__ tstate,
    float* __restrict__ out_cur, float* __restrict__ out_volt,
    float* lds, f2& V, f2& m, f2& h, f2& n, bool pub)
{
    const int t0 = p * KST;
    const float* sp = stim + (size_t)t0 * NSEG + sc0;

    // first PF stim loads issued BEFORE the spin (spin covers their latency)
    f2 stb[PF];
#pragma unroll
    for (int u = 0; u < PF; ++u)
        stb[u] = *(const f2*)(sp + (size_t)u * NSEG);
    __builtin_amdgcn_sched_barrier(0);

    // halo lanes (and everyone at p=0) spin on their own pair's 8 tagged
    // words; owned lanes keep exact state in registers across phases
    const bool needLoad = (!owned) || (p == 0);
    const u64* sb = tstate + (size_t)(p & 1) * 4 * NSEG + sc0;
    {
        u64 w0 = 0, w1 = 0, w2 = 0, w3 = 0, w4 = 0, w5 = 0, w6 = 0, w7 = 0;
        int ok;
        do {
            ok = 1;
            if (needLoad) {
                w0 = AL(sb);            w1 = AL(sb + 1);
                w2 = AL(sb + NSEG);     w3 = AL(sb + NSEG + 1);
                w4 = AL(sb + 2*NSEG);   w5 = AL(sb + 2*NSEG + 1);
                w6 = AL(sb + 3*NSEG);   w7 = AL(sb + 3*NSEG + 1);
                ok = (int)(w0 >> 32) >= p && (int)(w1 >> 32) >= p &&
                     (int)(w2 >> 32) >= p && (int)(w3 >> 32) >= p &&
                     (int)(w4 >> 32) >= p && (int)(w5 >> 32) >= p &&
                     (int)(w6 >> 32) >= p && (int)(w7 >> 32) >= p;
            }
        } while (!__all(ok));
        if (needLoad) {
            V.x = lo_f(w0); V.y = lo_f(w1);
            m.x = lo_f(w2); m.y = lo_f(w3);
            h.x = lo_f(w4); h.y = lo_f(w5);
            n.x = lo_f(w6); n.y = lo_f(w7);
        }
    }

    // K steps; rolling stim prefetch (static stb index under full unroll);
    // owned outputs buffered in LDS: row k = [mc[8] | vp[8] | pad2]
#pragma unroll
    for (int k = 0; k < KS; ++k) {
        const f2 is = stb[k & (PF - 1)];
        if (k + PF < KS)
            stb[k & (PF - 1)] = *(const f2*)(sp + (size_t)(k + PF) * NSEG);
        f2 mc, vp;
        hh_step2(V, m, h, n, is, le, re, gna, gk, gl, gax, mc, vp);
        if (owned) {
            float* lp = lds + k * LROW + 2 * (j - JLO);
            *(f2*)lp       = mc;              // 8B-aligned (LROW even)
            *(f2*)(lp + 8) = vp;
        }
    }

    // publish FIRST (MALL visibility latency hides under the dump below)
    if (pub && owned) {
        u64* pb = tstate + (size_t)((p + 1) & 1) * 4 * NSEG + s0;
        AS(pb,              pack_tag(V.x, p + 1));
        AS(pb + 1,          pack_tag(V.y, p + 1));
        AS(pb + NSEG,       pack_tag(m.x, p + 1));
        AS(pb + NSEG + 1,   pack_tag(m.y, p + 1));
        AS(pb + 2*NSEG,     pack_tag(h.x, p + 1));
        AS(pb + 2*NSEG + 1, pack_tag(h.y, p + 1));
        AS(pb + 3*NSEG,     pack_tag(n.x, p + 1));
        AS(pb + 3*NSEG + 1, pack_tag(n.y, p + 1));
    }
    __builtin_amdgcn_sched_barrier(0);

    // bulk-dump LDS -> global, all 64 lanes coalesced (16*KS % 64 == 0)
    const int sbase = b * COWN;
#pragma unroll
    for (int base = 0; base < 16 * KS; base += WAVE) {
        const int idx = base + j;
        const int t   = idx >> 4;
        const int q   = idx & 15;
        const float v = lds[t * LROW + q];
        const size_t go = (size_t)(t0 + t) * NSEG + sbase + (q & 7);
        if (q < 8) __builtin_nontemporal_store(v, out_cur + go);
        else       __builtin_nontemporal_store(v, out_volt + go);
    }
}

__global__ __launch_bounds__(WAVE, 1) void hh_persist(
    const float* __restrict__ stim,
    const float* __restrict__ gna_p, const float* __restrict__ gk_p,
    const float* __restrict__ gl_p,  const float* __restrict__ gax_p,
    u64* __restrict__ tstate,        // 2 buffers x 4 comps x NSEG tagged words
    float* __restrict__ out_cur, float* __restrict__ out_volt,
    float* __restrict__ tail)
{
    const int j = threadIdx.x;
    const int b = blockIdx.x;
    const int s0 = b * COWN - KST + 2 * j;          // even; may be out of range
    int sc0 = s0 < 0 ? 0 : (s0 > NSEG - 2 ? NSEG - 2 : s0);
    const bool owned = (j >= JLO) && (j < JLO + COWN / 2);
    const bool le = (s0 <= 0);                       // sealed left end
    const bool re = (s0 >= NSEG - 2);                // sealed right end

    const f2 gna = *(const f2*)(gna_p + sc0);
    const f2 gk  = *(const f2*)(gk_p  + sc0);
    const f2 gl  = *(const f2*)(gl_p  + sc0);
    const f2 gax = *(const f2*)(gax_p + sc0);

    __shared__ float lds[KST * LROW];

    f2 V = {0.f, 0.f}, m = V, h = V, n = V;

    for (int p = 0; p < NPH - 1; ++p)
        run_phase<KST>(p, b, j, s0, sc0, owned, le, re, gna, gk, gl, gax,
                       stim, tstate, out_cur, out_volt, lds, V, m, h, n, true);
    run_phase<KTAIL>(NPH - 1, b, j, s0, sc0, owned, le, re, gna, gk, gl, gax,
                     stim, tstate, out_cur, out_volt, lds, V, m, h, n, false);

    if (owned) {
        *(f2*)(tail + s0)            = V;
        *(f2*)(tail + NSEG + s0)     = m;
        *(f2*)(tail + 2 * NSEG + s0) = h;
        *(f2*)(tail + 3 * NSEG + s0) = n;
    }
}

__global__ void hh_init(const float* __restrict__ V0, const float* __restrict__ m0,
                        const float* __restrict__ h0, const float* __restrict__ n0,
                        u64* __restrict__ tstate)
{
    const int i = blockIdx.x * blockDim.x + threadIdx.x;
    if (i < NSEG) {
        // buffer 0 = publication for phase 0, tag 0
        tstate[i]            = pack_tag(V0[i], 0);
        tstate[NSEG + i]     = pack_tag(m0[i], 0);
        tstate[2 * NSEG + i] = pack_tag(h0[i], 0);
        tstate[3 * NSEG + i] = pack_tag(n0[i], 0);
        // buffer 1: invalid tag (replay determinism -- clear stale tags)
        u64* b1 = tstate + 4 * NSEG;
        const u64 inv = (u64)(u32)0x80000000u << 32;
        b1[i] = inv; b1[NSEG + i] = inv; b1[2 * NSEG + i] = inv; b1[3 * NSEG + i] = inv;
    }
}

extern "C" void kernel_launch(void* const* d_in, const int* in_sizes, int n_in,
                              void* d_out, int out_size, void* d_ws, size_t ws_size,
                              hipStream_t stream)
{
    const float* stim = (const float*)d_in[0];
    const float* V0   = (const float*)d_in[1];
    const float* m0   = (const float*)d_in[2];
    const float* h0   = (const float*)d_in[3];
    const float* n0   = (const float*)d_in[4];
    const float* gna  = (const float*)d_in[5];
    const float* gk   = (const float*)d_in[6];
    const float* gl   = (const float*)d_in[7];
    const float* gax  = (const float*)d_in[8];

    float* out      = (float*)d_out;
    float* out_cur  = out;
    float* out_volt = out + (size_t)TSTEPS * NSEG;
    float* tail     = out + 2 * (size_t)TSTEPS * NSEG;   // Vf, mf, hf, nf

    u64* tstate = (u64*)d_ws;    // 2 * 4 * NSEG tagged words = 128 KiB

    hipLaunchKernelGGL(hh_init, dim3(8), dim3(256), 0, stream,
                       V0, m0, h0, n0, tstate);
    hipLaunchKernelGGL(hh_persist, dim3(NBLK), dim3(WAVE), 0, stream,
                       stim, gna, gk, gl, gax, tstate,
                       out_cur, out_volt, tail);
}

// Round 9
// 1177.895 us; speedup vs baseline: 1.3675x; 1.3675x over previous
//
#include <hip/hip_runtime.h>

typedef unsigned long long u64;
typedef unsigned int u32;

#define TSTEPS 8192
#define NSEG   2048
#define DTC    0.025f

// Persistent single-wave halo decomposition (r7 structure): 256 blocks x
// 64 lanes, 1 seg/lane. Owned lanes 28..35 (8 segs) valid for K=28 steps.
// Fence-free sync via (tag<<32|f32bits) relaxed agent-scope atomics.
// r9: software-pipelined ds_bpermute neighbor exchange (issued right after
// V(t+1), consumed next step), precomputed clamped bpermute addresses,
// direct 3x rcp, mem_cur = fma(gax,ax,is).
#define KST    28
#define KTAIL  16
#define WAVE   64
#define COWN   8
#define NBLK   (NSEG / COWN)                 // 256
#define NPH    ((TSTEPS + KST - 1) / KST)    // 293 (292 full + 16-step tail)
#define JLO    KST                           // owned lanes [28, 36)
#define LDP    66                            // LDS row stride in float2s

constexpr double L2E = 1.4426950408889634074;   // log2(e)

#define AM_A ((float)(-0.1 * L2E))              // em0 = exp2(AM_A*V) = e^{-0.1V}
#define CEM  0.018315638888734179f              // e^-4    -> am's exp
#define CEH  0.030197383422318501f              // e^-3.5  -> bh's exp
#define CEN  0.0040867714384640666f             // e^-5.5  -> an's exp
#define BM_A ((float)(-L2E / 18.0))
#define BM_B ((float)(2.0 - 65.0 * L2E / 18.0)) // bm = 4e^{-(V+65)/18}
#define QA   ((float)(-L2E / 80.0))
#define QB   ((float)(-65.0 * L2E / 80.0))      // q = e^{-(V+65)/80}; bn=q/8; ah=0.07q^4
#define CAH  0.2645751311064591f                // sqrt(0.07)

#define AL(p) __hip_atomic_load((p), __ATOMIC_RELAXED, __HIP_MEMORY_SCOPE_AGENT)
#define AS(p, v) __hip_atomic_store((p), (v), __ATOMIC_RELAXED, __HIP_MEMORY_SCOPE_AGENT)

__device__ __forceinline__ u64 pack_tag(float v, int tag) {
    return ((u64)(u32)tag << 32) | (u64)__float_as_uint(v);
}
__device__ __forceinline__ float lo_f(u64 w) { return __uint_as_float((u32)w); }
__device__ __forceinline__ float bperm(int addr, float v) {
    return __int_as_float(__builtin_amdgcn_ds_bpermute(addr, __float_as_int(v)));
}

template <int KS>
__device__ __forceinline__ void run_phase(
    int p, int b, int j, int s, int sc,
    bool owned, int addrL, int addrR,
    float gna, float gk, float gl, float gax,
    const float* __restrict__ stim, u64* __restrict__ tstate,
    float* __restrict__ out_cur, float* __restrict__ out_volt,
    float* lds, float& V, float& m, float& h, float& n, bool pub)
{
    const int t0 = p * KST;
    const float* sp = stim + (size_t)t0 * NSEG + sc;

    // issue ALL stim loads for this phase, pinned before the spin
    float st[KS];
#pragma unroll
    for (int k = 0; k < KS; ++k)
        st[k] = sp[(size_t)k * NSEG];
    __builtin_amdgcn_sched_barrier(0);

    // halo lanes (and everyone at p=0) spin on their own slot's 4 tagged
    // words; owned lanes keep exact state in registers across phases
    const bool needLoad = (!owned) || (p == 0);
    const u64* sb = tstate + (size_t)(p & 1) * 4 * NSEG + sc;
    {
        u64 w0 = 0, w1 = 0, w2 = 0, w3 = 0;
        int ok;
        do {
            ok = 1;
            if (needLoad) {
                w0 = AL(sb);            w1 = AL(sb + NSEG);
                w2 = AL(sb + 2 * NSEG); w3 = AL(sb + 3 * NSEG);
                ok = (int)(w0 >> 32) >= p && (int)(w1 >> 32) >= p &&
                     (int)(w2 >> 32) >= p && (int)(w3 >> 32) >= p;
            }
        } while (!__all(ok));
        if (needLoad) {
            V = lo_f(w0); m = lo_f(w1); h = lo_f(w2); n = lo_f(w3);
        }
    }

    // prologue shuffles for step 0
    float Vl = bperm(addrL, V);
    float Vr = bperm(addrR, V);

    // K steps; pipelined: V(t+1) computed first, its shuffles issued
    // immediately, rate math runs under the DS latency
    float2* ld2 = (float2*)lds;
#pragma unroll
    for (int k = 0; k < KS; ++k) {
        const float is = st[k];
        const float ax = (Vl + Vr) - 2.0f * V;
        const float mc = __builtin_fmaf(gax, ax, is);     // mem_cur = i_ax + is
        const float m3 = m * m * m;
        const float n2 = n * n;
        const float i_ion = gna * m3 * h * (V - 50.0f)
                          + gk * (n2 * n2) * (V + 77.0f)
                          + gl * (V + 54.387f);
        const float dV = mc - i_ion;
        const float Vn = __builtin_fmaf(DTC, dV, V);
        const float VlN = bperm(addrL, Vn);               // fly under rate math
        const float VrN = bperm(addrR, Vn);

        ld2[k * LDP + j] = make_float2(mc, V);            // buffered output

        // rates from old V: 3 exp2 + 3 rcp, short chains
        const float em0 = __builtin_amdgcn_exp2f(V * AM_A);
        const float am  = __builtin_fmaf(0.1f, V, 4.0f) *
                          __builtin_amdgcn_rcpf(__builtin_fmaf(-CEM, em0, 1.0f));
        const float an  = __builtin_fmaf(0.01f, V, 0.55f) *
                          __builtin_amdgcn_rcpf(__builtin_fmaf(-CEN, em0, 1.0f));
        const float bh  = __builtin_amdgcn_rcpf(__builtin_fmaf(CEH, em0, 1.0f));
        const float bm  = __builtin_amdgcn_exp2f(__builtin_fmaf(V, BM_A, BM_B));
        const float q   = __builtin_amdgcn_exp2f(__builtin_fmaf(V, QA, QB));
        const float tq  = CAH * (q * q);
        const float ah  = tq * tq;                        // 0.07 * q^4
        const float bn  = 0.125f * q;

        m = __builtin_fmaf(DTC, __builtin_fmaf(-(am + bm), m, am), m);
        h = __builtin_fmaf(DTC, __builtin_fmaf(-(ah + bh), h, ah), h);
        n = __builtin_fmaf(DTC, __builtin_fmaf(-(an + bn), n, an), n);
        V = Vn; Vl = VlN; Vr = VrN;
    }

    // publish FIRST (MALL visibility latency hides under the dump below)
    if (pub && owned) {
        u64* pb = tstate + (size_t)((p + 1) & 1) * 4 * NSEG + s;
        AS(pb,            pack_tag(V, p + 1));
        AS(pb + NSEG,     pack_tag(m, p + 1));
        AS(pb + 2 * NSEG, pack_tag(h, p + 1));
        AS(pb + 3 * NSEG, pack_tag(n, p + 1));
    }
    __builtin_amdgcn_sched_barrier(0);

    // bulk-dump owned columns LDS -> global, all 64 lanes coalesced
    const int sbase = b * COWN;
#pragma unroll
    for (int base = 0; base < KS * COWN; base += WAVE) {
        const int idx = base + j;
        if (idx < KS * COWN) {
            const int t  = idx >> 3;
            const int sl = idx & 7;
            const float* lp = lds + (size_t)(t * LDP + JLO + sl) * 2;
            const size_t go = (size_t)(t0 + t) * NSEG + (sbase + sl);
            __builtin_nontemporal_store(lp[0], out_cur + go);
            __builtin_nontemporal_store(lp[1], out_volt + go);
        }
    }
}

__global__ __launch_bounds__(WAVE, 1) void hh_persist(
    const float* __restrict__ stim,
    const float* __restrict__ gna_p, const float* __restrict__ gk_p,
    const float* __restrict__ gl_p,  const float* __restrict__ gax_p,
    u64* __restrict__ tstate,        // 2 buffers x 4 comps x NSEG tagged words
    float* __restrict__ out_cur, float* __restrict__ out_volt,
    float* __restrict__ tail)
{
    const int j = threadIdx.x;
    const int b = blockIdx.x;
    const int s = b * COWN - KST + j;               // may be out of range (halo)
    const int sc = s < 0 ? 0 : (s > NSEG - 1 ? NSEG - 1 : s);
    const bool owned = (j >= JLO) && (j < JLO + COWN);

    // precomputed bpermute byte-addresses, sealed ends baked in (neighbor=
    // self). Wave-edge lanes read self: harmless, they're at cone distance K.
    const int jl = (s <= 0)        ? j : (j > 0  ? j - 1 : 0);
    const int jr = (s >= NSEG - 1) ? j : (j < 63 ? j + 1 : 63);
    const int addrL = jl * 4;
    const int addrR = jr * 4;

    const float gna = gna_p[sc], gk = gk_p[sc], gl = gl_p[sc], gax = gax_p[sc];

    __shared__ float lds[KST * LDP * 2];

    float V = 0.f, m = 0.f, h = 0.f, n = 0.f;

    for (int p = 0; p < NPH - 1; ++p)
        run_phase<KST>(p, b, j, s, sc, owned, addrL, addrR, gna, gk, gl, gax,
                       stim, tstate, out_cur, out_volt, lds, V, m, h, n, true);
    run_phase<KTAIL>(NPH - 1, b, j, s, sc, owned, addrL, addrR, gna, gk, gl, gax,
                     stim, tstate, out_cur, out_volt, lds, V, m, h, n, false);

    if (owned) {
        tail[s] = V; tail[NSEG + s] = m;
        tail[2 * NSEG + s] = h; tail[3 * NSEG + s] = n;
    }
}

__global__ void hh_init(const float* __restrict__ V0, const float* __restrict__ m0,
                        const float* __restrict__ h0, const float* __restrict__ n0,
                        u64* __restrict__ tstate)
{
    const int i = blockIdx.x * blockDim.x + threadIdx.x;
    if (i < NSEG) {
        // buffer 0 = publication for phase 0, tag 0
        tstate[i]            = pack_tag(V0[i], 0);
        tstate[NSEG + i]     = pack_tag(m0[i], 0);
        tstate[2 * NSEG + i] = pack_tag(h0[i], 0);
        tstate[3 * NSEG + i] = pack_tag(n0[i], 0);
        // buffer 1: invalid tag (replay determinism -- clear stale tags)
        u64* b1 = tstate + 4 * NSEG;
        const u64 inv = (u64)(u32)0x80000000u << 32;
        b1[i] = inv; b1[NSEG + i] = inv; b1[2 * NSEG + i] = inv; b1[3 * NSEG + i] = inv;
    }
}

extern "C" void kernel_launch(void* const* d_in, const int* in_sizes, int n_in,
                              void* d_out, int out_size, void* d_ws, size_t ws_size,
                              hipStream_t stream)
{
    const float* stim = (const float*)d_in[0];
    const float* V0   = (const float*)d_in[1];
    const float* m0   = (const float*)d_in[2];
    const float* h0   = (const float*)d_in[3];
    const float* n0   = (const float*)d_in[4];
    const float* gna  = (const float*)d_in[5];
    const float* gk   = (const float*)d_in[6];
    const float* gl   = (const float*)d_in[7];
    const float* gax  = (const float*)d_in[8];

    float* out      = (float*)d_out;
    float* out_cur  = out;
    float* out_volt = out + (size_t)TSTEPS * NSEG;
    float* tail     = out + 2 * (size_t)TSTEPS * NSEG;   // Vf, mf, hf, nf

    u64* tstate = (u64*)d_ws;    // 2 * 4 * NSEG tagged words = 128 KiB

    hipLaunchKernelGGL(hh_init, dim3(8), dim3(256), 0, stream,
                       V0, m0, h0, n0, tstate);
    hipLaunchKernelGGL(hh_persist, dim3(NBLK), dim3(WAVE), 0, stream,
                       stim, gna, gk, gl, gax, tstate,
                       out_cur, out_volt, tail);
}